// Round 5
// baseline (862.865 us; speedup 1.0000x reference)
//
#include <hip/hip_runtime.h>

// DynamicFilter fused, R5: conv2 via bf16 MFMA implicit GEMM, conv1 tap-streamed.
//
// R4 was LDS-pipe + VALU co-limited (SQ_LDS_BANK_CONFLICT ~1e8, conv1 re-read
// the x-window per channel: 2688 ds_read_b32/thread; conv2 28.8K scalar FMAs).
// R5:
//  * conv2 = tap-pair GEMM on mfma_f32_16x16x32_bf16: D[16f][16px] over
//    K=32 (2 taps x 16ch), 13 tap-pairs x 2 channel-phases. h stored bf16
//    channel-minor, ch padded 16->24 (48B px stride -> <=2-way bank alias).
//    B-fragment = one aligned ds_read_b128/lane. A (w2) pre-transposed to
//    d_ws by a prep kernel: w2t[26tap][16f][32ch] bf16, tap25 & f>=9 zeroed
//    (zero A rows neutralize pad taps/filters, incl. the clamped B address).
//  * conv1 = 1 thread/px, stream 50 taps: 1 LDS read feeds 16 FMAs; weights
//    uniform s_loads from w1t[50tap][32ch] (prep kernel). 4.5x fewer LDS ops.
//  * epilogue: per-quarter-wave partial dot with eye-expanded image from xs,
//    shfl_down(16)+shfl_down(32) reduce, lanes 0-15 store 64B/row.
// d_ws usage: w1t fp32 @0 (6.4KB), w2t bf16 @8192 (26.6KB) = 34.8KB total.
// LDS: xs 12.8KB + hs 62.2KB = 75.0KB -> 2 blocks/CU. VGPR ~145 (acc 64 +
// A-frags 52) -> waves_per_eu(2,2) matches the LDS-capped occupancy.

typedef __attribute__((ext_vector_type(8))) short bf16x8;
typedef __attribute__((ext_vector_type(4))) float f32x4;

#define HH 512
#define WW 512
#define TILE 32
#define XS_H 40
#define XS_W 40
#define HS_R 36
#define HS_C 36
#define CHP 24   // channel pad per phase (16 used) -> 48B px stride

__device__ __forceinline__ unsigned short f2bf(float x) {
    union { float f; unsigned int u; } v; v.f = x;
    unsigned int u = v.u;
    u += 0x7FFFu + ((u >> 16) & 1u);   // round-to-nearest-even
    return (unsigned short)(u >> 16);
}

__global__ void dynfilt_prep(const float* __restrict__ w1,
                             const float* __restrict__ w2,
                             float* __restrict__ w1t,
                             unsigned short* __restrict__ w2t)
{
    int t = threadIdx.x;
    // w1t[tap][ch]: tap = ci*25 + dy*5 + dx; w1 is [32ch][2ci][5][5]
    for (int i = t; i < 50 * 32; i += 256) {
        int tap = i >> 5, ch = i & 31;
        int ci = tap / 25, r = tap - ci * 25;
        w1t[i] = w1[(ch * 2 + ci) * 25 + r];
    }
    // w2t[tap26][f16][ch32] bf16; w2 is [9f][32ch][5][5]; zero pad tap/f
    for (int i = t; i < 26 * 16 * 32; i += 256) {
        int ch = i & 31;
        int f = (i >> 5) & 15;
        int tap = i >> 9;
        unsigned short v = 0;
        if (tap < 25 && f < 9) v = f2bf(w2[(f * 32 + ch) * 25 + tap]);
        w2t[i] = v;
    }
}

__global__
__attribute__((amdgpu_flat_work_group_size(256, 256), amdgpu_waves_per_eu(2, 2)))
void dynfilt_main(const float* __restrict__ image,
                  const float* __restrict__ refer,
                  const float* __restrict__ b1,
                  const float* __restrict__ b2,
                  const float* __restrict__ w1t,
                  const unsigned short* __restrict__ w2t,
                  float* __restrict__ out)
{
    __shared__ float xs[2][XS_H][XS_W];
    __shared__ unsigned short hs[HS_R * HS_C * CHP];

    const int t   = threadIdx.x;
    const int gx0 = blockIdx.x * TILE;
    const int gy0 = blockIdx.y * TILE;
    const int b   = blockIdx.z;

    // ---- stage x halo: rows gy0-4..gy0+35, cols gx0-4..gx0+35, 2 channels ----
    for (int idx = t; idx < 2 * XS_H * XS_W; idx += 256) {
        int ci  = idx / (XS_H * XS_W);
        int rem = idx - ci * (XS_H * XS_W);
        int r = rem / XS_W, c = rem - r * XS_W;
        int gy = gy0 - 4 + r, gx = gx0 - 4 + c;
        float v = 0.f;
        if ((unsigned)gy < HH && (unsigned)gx < WW)
            v = (ci ? refer : image)[((size_t)b * HH + gy) * WW + gx];
        (&xs[0][0][0])[idx] = v;
    }

    const int lane = t & 63;
    const int wv   = t >> 6;
    const int n    = lane & 15;        // MFMA m/n index (filter for A, px for B)
    const int kg   = lane >> 4;        // k-group 0..3
    const int kgh  = kg >> 1;          // which tap of the pair
    const int chb  = (kg & 1) * 8;     // channel sub-block within phase

    // per-lane hs byte offset for each tap-pair (computed once)
    int bofs[13];
    #pragma unroll
    for (int tp = 0; tp < 13; ++tp) {
        int tap = 2 * tp + kgh;
        if (tap > 24) tap = 0;         // pad tap: A row is zero, any addr safe
        int dy = tap / 5, dx = tap - dy * 5;
        bofs[tp] = ((dy * HS_C + dx) * CHP + chb) * 2;
    }

    f32x4 acc[16];
    #pragma unroll
    for (int i = 0; i < 16; ++i) acc[i] = (f32x4){0.f, 0.f, 0.f, 0.f};

    #pragma unroll 1
    for (int p = 0; p < 2; ++p) {
        __syncthreads();   // xs ready (p0) / prev-phase MFMA reads done (p1)

        // ---- conv1: channels [16p, 16p+16) -> hs bf16 ch-minor ----
        #pragma unroll 1
        for (int it = 0; it < 6; ++it) {
            int idx = it * 256 + t;
            if (idx < HS_R * HS_C) {
                int r = idx / HS_C, c = idx - r * HS_C;
                int gy = gy0 - 2 + r, gx = gx0 - 2 + c;
                bool inb = ((unsigned)gy < HH) & ((unsigned)gx < WW);
                float a1[16];
                #pragma unroll
                for (int ch = 0; ch < 16; ++ch) a1[ch] = 0.f;
                if (inb) {
                    #pragma unroll 1
                    for (int ci = 0; ci < 2; ++ci) {
                        #pragma unroll 1
                        for (int dy = 0; dy < 5; ++dy) {
                            const float* xrow = &xs[ci][r + dy][c];
                            float rv[5];
                            #pragma unroll
                            for (int dx = 0; dx < 5; ++dx) rv[dx] = xrow[dx];
                            #pragma unroll 1
                            for (int cb = 0; cb < 2; ++cb) {   // cap live s-weights at 40
                                const float* wr = w1t + (ci * 25 + dy * 5) * 32 + p * 16 + cb * 8;
                                #pragma unroll
                                for (int dx = 0; dx < 5; ++dx) {
                                    #pragma unroll
                                    for (int ch = 0; ch < 8; ++ch)
                                        a1[cb * 8 + ch] += rv[dx] * wr[dx * 32 + ch];
                                }
                            }
                        }
                    }
                }
                unsigned int pk[8];
                #pragma unroll
                for (int ch = 0; ch < 8; ++ch) {
                    float v0 = 0.f, v1 = 0.f;
                    if (inb) {
                        v0 = a1[2 * ch]     + b1[p * 16 + 2 * ch];
                        v1 = a1[2 * ch + 1] + b1[p * 16 + 2 * ch + 1];
                        v0 = (v0 >= 0.f) ? v0 : 0.1f * v0;
                        v1 = (v1 >= 0.f) ? v1 : 0.1f * v1;
                    }
                    pk[ch] = ((unsigned)f2bf(v1) << 16) | (unsigned)f2bf(v0);
                }
                unsigned short* hp = &hs[idx * CHP];
                ((uint4*)hp)[0] = make_uint4(pk[0], pk[1], pk[2], pk[3]);
                *((uint4*)(hp + 8)) = make_uint4(pk[4], pk[5], pk[6], pk[7]);
            }
        }
        __syncthreads();   // hs ready

        // ---- A fragments for this phase (w2t is L1/L2-hot, 16B loads) ----
        bf16x8 afr[13];
        #pragma unroll
        for (int tp = 0; tp < 13; ++tp) {
            int tap = 2 * tp + kgh;    // tap 25 exists in w2t and is zero
            afr[tp] = *(const bf16x8*)(w2t + (tap * 16 + n) * 32 + p * 16 + chb);
        }

        // ---- conv2: 16 N-tiles per wave, 13 MFMAs each ----
        #pragma unroll 2
        for (int i = 0; i < 16; ++i) {
            int tile = wv * 16 + i;
            int py = tile >> 1, px0 = (tile & 1) * 16;
            const char* bbase = (const char*)hs + ((py * HS_C + px0 + n) * CHP) * 2;
            f32x4 cacc = acc[i];
            #pragma unroll
            for (int tp = 0; tp < 13; ++tp) {
                bf16x8 bfrag = *(const bf16x8*)(bbase + bofs[tp]);
                cacc = __builtin_amdgcn_mfma_f32_16x16x32_bf16(afr[tp], bfrag, cacc, 0, 0, 0);
            }
            acc[i] = cacc;
        }
    }

    // ---- epilogue: out = sum_f (filt_f + b2_f) * image[y+fy-1][x+fx-1] ----
    // lane holds filters f = kg*4 + r2 for pixel n; f>=9 rows are exact zeros.
    float b2r[4];
    int fyr[4], fxr[4];
    #pragma unroll
    for (int r2 = 0; r2 < 4; ++r2) {
        int f = kg * 4 + r2;
        b2r[r2] = (f < 9) ? b2[f] : 0.f;
        int fy = f / 3;
        fyr[r2] = fy; fxr[r2] = f - fy * 3;
    }
    #pragma unroll 1
    for (int i = 0; i < 16; ++i) {
        int tile = wv * 16 + i;
        int py = tile >> 1, px0 = (tile & 1) * 16;
        float partial = 0.f;
        #pragma unroll
        for (int r2 = 0; r2 < 4; ++r2) {
            float img = xs[0][py + fyr[r2] + 3][px0 + n + fxr[r2] + 3];
            partial += (acc[i][r2] + b2r[r2]) * img;   // zero term for f>=9
        }
        partial += __shfl_down(partial, 16, 64);
        partial += __shfl_down(partial, 32, 64);
        if (lane < 16)
            out[((size_t)b * HH + gy0 + py) * WW + gx0 + px0 + n] = partial;
    }
}

extern "C" void kernel_launch(void* const* d_in, const int* in_sizes, int n_in,
                              void* d_out, int out_size, void* d_ws, size_t ws_size,
                              hipStream_t stream) {
    const float* image = (const float*)d_in[0];
    const float* refer = (const float*)d_in[1];
    const float* w1    = (const float*)d_in[2];
    const float* b1    = (const float*)d_in[3];
    const float* w2    = (const float*)d_in[4];
    const float* b2    = (const float*)d_in[5];

    float* w1t = (float*)d_ws;                                   // 6.4 KB
    unsigned short* w2t = (unsigned short*)((char*)d_ws + 8192); // 26.6 KB
    // ws re-poisoned before every launch -> prep must (and does) run every call

    hipLaunchKernelGGL(dynfilt_prep, dim3(1), dim3(256), 0, stream, w1, w2, w1t, w2t);

    dim3 grid(WW / TILE, HH / TILE, 8);
    hipLaunchKernelGGL(dynfilt_main, grid, dim3(256), 0, stream,
                       image, refer, b1, b2, w1t, w2t, (float*)d_out);
}

// Round 6
// 826.534 us; speedup vs baseline: 1.0440x; 1.0440x over previous
//
#include <hip/hip_runtime.h>

// DynamicFilter fused, R6: fix R5's scratch-spill of the accumulator array.
//
// R5 used "#pragma unroll 2" over the 16 conv2 tiles and "unroll 1" in the
// epilogue while indexing acc[i] -> runtime-indexed register array -> all 16
// f32x4 accumulators demoted to scratch (WRITE_SIZE 352 MB vs 8.4 MB output,
// 863 us). R6 fully unrolls both loops so acc indices are compile-time and
// the accumulators stay in the unified VGPR/AGPR file (~150-170 regs live,
// fits 2-waves/EU budget).
//
// Structure (unchanged from R5, which validated correct at absmax 0.031):
//  * conv2 = tap-pair GEMM on mfma_f32_16x16x32_bf16: D[16f][16px] over
//    K=32 (2 taps x 16ch), 13 tap-pairs x 2 channel-phases. h stored bf16
//    channel-minor, ch padded 16->24 (48B px stride -> <=2-way bank alias).
//    B-fragment = one aligned ds_read_b128/lane. A (w2) pre-transposed to
//    d_ws by a prep kernel: w2t[26tap][16f][32ch] bf16, tap25 & f>=9 zeroed.
//  * conv1 = 1 thread/px, stream 50 taps: 1 LDS read feeds 16 FMAs; weights
//    uniform s_loads from w1t[50tap][32ch] (prep kernel).
//  * epilogue: per-quarter-wave partial dot + shfl_down(16/32) reduce.
// d_ws: w1t fp32 @0 (6.4KB), w2t bf16 @8192 (26.6KB).
// LDS: xs 12.8KB + hs 62.2KB = 75.0KB -> 2 blocks/CU.

typedef __attribute__((ext_vector_type(8))) short bf16x8;
typedef __attribute__((ext_vector_type(4))) float f32x4;

#define HH 512
#define WW 512
#define TILE 32
#define XS_H 40
#define XS_W 40
#define HS_R 36
#define HS_C 36
#define CHP 24   // channel pad per phase (16 used) -> 48B px stride

__device__ __forceinline__ unsigned short f2bf(float x) {
    union { float f; unsigned int u; } v; v.f = x;
    unsigned int u = v.u;
    u += 0x7FFFu + ((u >> 16) & 1u);   // round-to-nearest-even
    return (unsigned short)(u >> 16);
}

__global__ void dynfilt_prep(const float* __restrict__ w1,
                             const float* __restrict__ w2,
                             float* __restrict__ w1t,
                             unsigned short* __restrict__ w2t)
{
    int t = threadIdx.x;
    // w1t[tap][ch]: tap = ci*25 + dy*5 + dx; w1 is [32ch][2ci][5][5]
    for (int i = t; i < 50 * 32; i += 256) {
        int tap = i >> 5, ch = i & 31;
        int ci = tap / 25, r = tap - ci * 25;
        w1t[i] = w1[(ch * 2 + ci) * 25 + r];
    }
    // w2t[tap26][f16][ch32] bf16; w2 is [9f][32ch][5][5]; zero pad tap/f
    for (int i = t; i < 26 * 16 * 32; i += 256) {
        int ch = i & 31;
        int f = (i >> 5) & 15;
        int tap = i >> 9;
        unsigned short v = 0;
        if (tap < 25 && f < 9) v = f2bf(w2[(f * 32 + ch) * 25 + tap]);
        w2t[i] = v;
    }
}

__global__
__attribute__((amdgpu_flat_work_group_size(256, 256), amdgpu_waves_per_eu(2, 2)))
void dynfilt_main(const float* __restrict__ image,
                  const float* __restrict__ refer,
                  const float* __restrict__ b1,
                  const float* __restrict__ b2,
                  const float* __restrict__ w1t,
                  const unsigned short* __restrict__ w2t,
                  float* __restrict__ out)
{
    __shared__ float xs[2][XS_H][XS_W];
    __shared__ unsigned short hs[HS_R * HS_C * CHP];

    const int t   = threadIdx.x;
    const int gx0 = blockIdx.x * TILE;
    const int gy0 = blockIdx.y * TILE;
    const int b   = blockIdx.z;

    // ---- stage x halo: rows gy0-4..gy0+35, cols gx0-4..gx0+35, 2 channels ----
    for (int idx = t; idx < 2 * XS_H * XS_W; idx += 256) {
        int ci  = idx / (XS_H * XS_W);
        int rem = idx - ci * (XS_H * XS_W);
        int r = rem / XS_W, c = rem - r * XS_W;
        int gy = gy0 - 4 + r, gx = gx0 - 4 + c;
        float v = 0.f;
        if ((unsigned)gy < HH && (unsigned)gx < WW)
            v = (ci ? refer : image)[((size_t)b * HH + gy) * WW + gx];
        (&xs[0][0][0])[idx] = v;
    }

    const int lane = t & 63;
    const int wv   = t >> 6;
    const int n    = lane & 15;        // MFMA m/n index (filter for A, px for B)
    const int kg   = lane >> 4;        // k-group 0..3
    const int kgh  = kg >> 1;          // which tap of the pair
    const int chb  = (kg & 1) * 8;     // channel sub-block within phase

    // per-lane hs byte offset for each tap-pair (computed once)
    int bofs[13];
    #pragma unroll
    for (int tp = 0; tp < 13; ++tp) {
        int tap = 2 * tp + kgh;
        if (tap > 24) tap = 0;         // pad tap: A row is zero, any addr safe
        int dy = tap / 5, dx = tap - dy * 5;
        bofs[tp] = ((dy * HS_C + dx) * CHP + chb) * 2;
    }

    f32x4 acc[16];
    #pragma unroll
    for (int i = 0; i < 16; ++i) acc[i] = (f32x4){0.f, 0.f, 0.f, 0.f};

    #pragma unroll 1
    for (int p = 0; p < 2; ++p) {
        __syncthreads();   // xs ready (p0) / prev-phase MFMA reads done (p1)

        // ---- conv1: channels [16p, 16p+16) -> hs bf16 ch-minor ----
        #pragma unroll 1
        for (int it = 0; it < 6; ++it) {
            int idx = it * 256 + t;
            if (idx < HS_R * HS_C) {
                int r = idx / HS_C, c = idx - r * HS_C;
                int gy = gy0 - 2 + r, gx = gx0 - 2 + c;
                bool inb = ((unsigned)gy < HH) & ((unsigned)gx < WW);
                float a1[16];
                #pragma unroll
                for (int ch = 0; ch < 16; ++ch) a1[ch] = 0.f;
                if (inb) {
                    #pragma unroll 1
                    for (int ci = 0; ci < 2; ++ci) {
                        #pragma unroll 1
                        for (int dy = 0; dy < 5; ++dy) {
                            const float* xrow = &xs[ci][r + dy][c];
                            float rv[5];
                            #pragma unroll
                            for (int dx = 0; dx < 5; ++dx) rv[dx] = xrow[dx];
                            #pragma unroll 1
                            for (int cb = 0; cb < 2; ++cb) {   // cap live s-weights at 40
                                const float* wr = w1t + (ci * 25 + dy * 5) * 32 + p * 16 + cb * 8;
                                #pragma unroll
                                for (int dx = 0; dx < 5; ++dx) {
                                    #pragma unroll
                                    for (int ch = 0; ch < 8; ++ch)
                                        a1[cb * 8 + ch] += rv[dx] * wr[dx * 32 + ch];
                                }
                            }
                        }
                    }
                }
                unsigned int pk[8];
                #pragma unroll
                for (int ch = 0; ch < 8; ++ch) {
                    float v0 = 0.f, v1 = 0.f;
                    if (inb) {
                        v0 = a1[2 * ch]     + b1[p * 16 + 2 * ch];
                        v1 = a1[2 * ch + 1] + b1[p * 16 + 2 * ch + 1];
                        v0 = (v0 >= 0.f) ? v0 : 0.1f * v0;
                        v1 = (v1 >= 0.f) ? v1 : 0.1f * v1;
                    }
                    pk[ch] = ((unsigned)f2bf(v1) << 16) | (unsigned)f2bf(v0);
                }
                unsigned short* hp = &hs[idx * CHP];
                ((uint4*)hp)[0] = make_uint4(pk[0], pk[1], pk[2], pk[3]);
                *((uint4*)(hp + 8)) = make_uint4(pk[4], pk[5], pk[6], pk[7]);
            }
        }
        __syncthreads();   // hs ready

        // ---- A fragments for this phase (w2t is L1/L2-hot, 16B loads) ----
        bf16x8 afr[13];
        #pragma unroll
        for (int tp = 0; tp < 13; ++tp) {
            int tap = 2 * tp + kgh;    // tap 25 exists in w2t and is zero
            afr[tp] = *(const bf16x8*)(w2t + (tap * 16 + n) * 32 + p * 16 + chb);
        }

        // ---- conv2: 16 N-tiles per wave, 13 MFMAs each (FULL unroll:
        //      acc[i] must be compile-time indexed or it spills to scratch) ----
        #pragma unroll
        for (int i = 0; i < 16; ++i) {
            int tile = wv * 16 + i;
            int py = tile >> 1, px0 = (tile & 1) * 16;
            const char* bbase = (const char*)hs + ((py * HS_C + px0 + n) * CHP) * 2;
            f32x4 cacc = acc[i];
            #pragma unroll
            for (int tp = 0; tp < 13; ++tp) {
                bf16x8 bfrag = *(const bf16x8*)(bbase + bofs[tp]);
                cacc = __builtin_amdgcn_mfma_f32_16x16x32_bf16(afr[tp], bfrag, cacc, 0, 0, 0);
            }
            acc[i] = cacc;
        }
    }

    // ---- epilogue: out = sum_f (filt_f + b2_f) * image[y+fy-1][x+fx-1] ----
    // lane holds filters f = kg*4 + r2 for pixel n; f>=9 rows are exact zeros.
    float b2r[4];
    int fyr[4], fxr[4];
    #pragma unroll
    for (int r2 = 0; r2 < 4; ++r2) {
        int f = kg * 4 + r2;
        b2r[r2] = (f < 9) ? b2[f] : 0.f;
        int fy = f / 3;
        fyr[r2] = fy; fxr[r2] = f - fy * 3;
    }
    #pragma unroll
    for (int i = 0; i < 16; ++i) {   // FULL unroll: compile-time acc index
        int tile = wv * 16 + i;
        int py = tile >> 1, px0 = (tile & 1) * 16;
        float partial = 0.f;
        #pragma unroll
        for (int r2 = 0; r2 < 4; ++r2) {
            float img = xs[0][py + fyr[r2] + 3][px0 + n + fxr[r2] + 3];
            partial += (acc[i][r2] + b2r[r2]) * img;   // zero term for f>=9
        }
        partial += __shfl_down(partial, 16, 64);
        partial += __shfl_down(partial, 32, 64);
        if (lane < 16)
            out[((size_t)b * HH + gy0 + py) * WW + gx0 + px0 + n] = partial;
    }
}

extern "C" void kernel_launch(void* const* d_in, const int* in_sizes, int n_in,
                              void* d_out, int out_size, void* d_ws, size_t ws_size,
                              hipStream_t stream) {
    const float* image = (const float*)d_in[0];
    const float* refer = (const float*)d_in[1];
    const float* w1    = (const float*)d_in[2];
    const float* b1    = (const float*)d_in[3];
    const float* w2    = (const float*)d_in[4];
    const float* b2    = (const float*)d_in[5];

    float* w1t = (float*)d_ws;                                   // 6.4 KB
    unsigned short* w2t = (unsigned short*)((char*)d_ws + 8192); // 26.6 KB
    // ws re-poisoned before every launch -> prep must (and does) run every call

    hipLaunchKernelGGL(dynfilt_prep, dim3(1), dim3(256), 0, stream, w1, w2, w1t, w2t);

    dim3 grid(WW / TILE, HH / TILE, 8);
    hipLaunchKernelGGL(dynfilt_main, grid, dim3(256), 0, stream,
                       image, refer, b1, b2, w1t, w2t, (float*)d_out);
}

// Round 7
// 260.646 us; speedup vs baseline: 3.3105x; 3.1711x over previous
//
#include <hip/hip_runtime.h>

// DynamicFilter fused, R7: 16x16 tile, single-phase (all 32 ch), 4 blocks/CU.
//
// R6 was latency-bound: 2 waves/SIMD (75KB LDS) couldn't hide s_load->FMA,
// ds_read->MFMA and 13-deep MFMA chains (MfmaUtil 2.9%, VALUBusy 50%, 47%
// idle). R7 shrinks the tile so conv1 runs ONCE (no phases):
//  * xs 2x24x24 fp32 (4.6KB) + hs 400px x 32ch bf16, px stride 80B (32KB)
//    -> 36.6KB LDS -> 4 blocks/CU = 4 waves/SIMD, only 2 barriers/block.
//  * conv1: 1 thread/px (400 px, 256 thr, 2 sweeps), x read once (50 reads),
//    feeds 32 FMAs each; weights uniform s_loads from w1t[50tap][32ch].
//    a1[32] compile-time indexed everywhere (R5 spill lesson).
//  * conv2: tap-quad MFMA GEMM, K=32 = 4tap x 8ch: 7 quad-sets x 4 ch-groups
//    x 4 tiles(16px rows)/wave = 112 mfma_f32_16x16x32_bf16 per wave.
//    A-frags streamed per-q from w2t[28tap][16f][32ch] (taps>=25,f>=9 zero),
//    only 16 A-regs live. B = one aligned ds_read_b128 (80B stride: 2-way
//    bank alias = free).
//  * epilogue: lane(kg*4+r2)=filter f, shfl_down(16/32) reduce, lanes 0-15
//    store (verified R5/R6 mapping).
// d_ws: w1t fp32 @0 (6.4KB), w2t bf16 @8192 (28.7KB).

typedef __attribute__((ext_vector_type(8))) short bf16x8;
typedef __attribute__((ext_vector_type(4))) float f32x4;

#define HH 512
#define WW 512
#define TILE 16
#define XS_H 24
#define XS_W 24
#define HS_R 20
#define HS_C 20
#define HSTRIDE 40   // shorts per px (32 used, 8 pad) -> 80B, 2-way alias only

__device__ __forceinline__ unsigned short f2bf(float x) {
    union { float f; unsigned int u; } v; v.f = x;
    unsigned int u = v.u;
    u += 0x7FFFu + ((u >> 16) & 1u);   // round-to-nearest-even
    return (unsigned short)(u >> 16);
}

__global__ void dynfilt_prep(const float* __restrict__ w1,
                             const float* __restrict__ w2,
                             float* __restrict__ w1t,
                             unsigned short* __restrict__ w2t)
{
    int t = threadIdx.x;
    // w1t[tap50][ch32]: tap = ci*25 + dy*5 + dx; w1 is [32ch][2ci][5][5]
    for (int i = t; i < 50 * 32; i += 256) {
        int tap = i >> 5, ch = i & 31;
        int ci = tap / 25, r = tap - ci * 25;
        w1t[i] = w1[(ch * 2 + ci) * 25 + r];
    }
    // w2t[tap28][f16][ch32] bf16; w2 is [9f][32ch][5][5]; taps>=25 / f>=9 zero
    for (int i = t; i < 28 * 16 * 32; i += 256) {
        int ch = i & 31;
        int f = (i >> 5) & 15;
        int tap = i >> 9;
        unsigned short v = 0;
        if (tap < 25 && f < 9) v = f2bf(w2[(f * 32 + ch) * 25 + tap]);
        w2t[i] = v;
    }
}

__global__
__attribute__((amdgpu_flat_work_group_size(256, 256), amdgpu_waves_per_eu(4)))
void dynfilt_main(const float* __restrict__ image,
                  const float* __restrict__ refer,
                  const float* __restrict__ b1,
                  const float* __restrict__ b2,
                  const float* __restrict__ w1t,
                  const unsigned short* __restrict__ w2t,
                  float* __restrict__ out)
{
    __shared__ float xs[2][XS_H][XS_W];
    __shared__ unsigned short hs[HS_R * HS_C * HSTRIDE];

    const int t   = threadIdx.x;
    const int gx0 = blockIdx.x * TILE;
    const int gy0 = blockIdx.y * TILE;
    const int b   = blockIdx.z;

    // ---- stage x halo: rows gy0-4..gy0+19, cols gx0-4..gx0+19, 2 ch ----
    for (int idx = t; idx < 2 * XS_H * XS_W; idx += 256) {
        int ci  = idx / (XS_H * XS_W);
        int rem = idx - ci * (XS_H * XS_W);
        int r = rem / XS_W, c = rem - r * XS_W;
        int gy = gy0 - 4 + r, gx = gx0 - 4 + c;
        float v = 0.f;
        if ((unsigned)gy < HH && (unsigned)gx < WW)
            v = (ci ? refer : image)[((size_t)b * HH + gy) * WW + gx];
        (&xs[0][0][0])[idx] = v;
    }
    __syncthreads();   // xs ready (covers conv1 + epilogue reads)

    // ---- conv1: all 32 channels, one pass over 20x20 h pixels ----
    #pragma unroll 1
    for (int it = 0; it < 2; ++it) {
        int idx = it * 256 + t;
        if (idx < HS_R * HS_C) {
            int r = idx / HS_C, c = idx - r * HS_C;
            int gy = gy0 - 2 + r, gx = gx0 - 2 + c;
            bool inb = ((unsigned)gy < HH) & ((unsigned)gx < WW);
            float a1[32];
            #pragma unroll
            for (int ch = 0; ch < 32; ++ch) a1[ch] = 0.f;
            if (inb) {
                #pragma unroll 1
                for (int ci = 0; ci < 2; ++ci) {
                    #pragma unroll 1
                    for (int dy = 0; dy < 5; ++dy) {   // unroll1: bound live s-weights
                        const float* xrow = &xs[ci][r + dy][c];
                        float rv[5];
                        #pragma unroll
                        for (int dx = 0; dx < 5; ++dx) rv[dx] = xrow[dx];
                        const float* wr = w1t + (ci * 25 + dy * 5) * 32;
                        #pragma unroll
                        for (int dx = 0; dx < 5; ++dx)
                            #pragma unroll
                            for (int ch = 0; ch < 32; ++ch)
                                a1[ch] += rv[dx] * wr[dx * 32 + ch];
                    }
                }
            }
            unsigned int pk[16];
            #pragma unroll
            for (int ch = 0; ch < 16; ++ch) {
                float v0 = 0.f, v1 = 0.f;
                if (inb) {
                    v0 = a1[2 * ch]     + b1[2 * ch];
                    v1 = a1[2 * ch + 1] + b1[2 * ch + 1];
                    v0 = (v0 >= 0.f) ? v0 : 0.1f * v0;
                    v1 = (v1 >= 0.f) ? v1 : 0.1f * v1;
                }
                pk[ch] = ((unsigned)f2bf(v1) << 16) | (unsigned)f2bf(v0);
            }
            unsigned short* hp = &hs[idx * HSTRIDE];
            ((uint4*)hp)[0] = make_uint4(pk[0],  pk[1],  pk[2],  pk[3]);
            ((uint4*)hp)[1] = make_uint4(pk[4],  pk[5],  pk[6],  pk[7]);
            ((uint4*)hp)[2] = make_uint4(pk[8],  pk[9],  pk[10], pk[11]);
            ((uint4*)hp)[3] = make_uint4(pk[12], pk[13], pk[14], pk[15]);
        }
    }
    __syncthreads();   // hs ready

    const int lane = t & 63;
    const int wv   = t >> 6;
    const int n    = lane & 15;        // MFMA m/n index (filter for A, px for B)
    const int kg   = lane >> 4;        // k-group: tap within quad

    // per-lane B byte offsets per quad-set (tap = q*4+kg; >24 -> A row zero)
    int bofs[7];
    #pragma unroll
    for (int q = 0; q < 7; ++q) {
        int tap = 4 * q + kg;
        if (tap > 24) tap = 0;
        int dy = tap / 5, dx = tap - dy * 5;
        bofs[q] = (dy * HS_C + dx) * (HSTRIDE * 2);
    }

    // per-tile base: tile i covers output row py = wv*4+i, px n
    const char* bb[4];
    #pragma unroll
    for (int i = 0; i < 4; ++i)
        bb[i] = (const char*)hs + ((wv * 4 + i) * HS_C + n) * (HSTRIDE * 2);

    f32x4 acc[4];
    #pragma unroll
    for (int i = 0; i < 4; ++i) acc[i] = (f32x4){0.f, 0.f, 0.f, 0.f};

    // ---- conv2: 7 quad-sets x 4 ch-groups x 4 tiles of MFMA ----
    #pragma unroll
    for (int q = 0; q < 7; ++q) {
        bf16x8 afr[4];
        #pragma unroll
        for (int g = 0; g < 4; ++g)
            afr[g] = *(const bf16x8*)(w2t + ((4 * q + kg) * 16 + n) * 32 + g * 8);
        #pragma unroll
        for (int i = 0; i < 4; ++i) {
            const char* ba = bb[i] + bofs[q];
            #pragma unroll
            for (int g = 0; g < 4; ++g) {
                bf16x8 bfrag = *(const bf16x8*)(ba + g * 16);
                acc[i] = __builtin_amdgcn_mfma_f32_16x16x32_bf16(afr[g], bfrag, acc[i], 0, 0, 0);
            }
        }
    }

    // ---- epilogue: out = sum_f (filt_f + b2_f) * image[y+fy-1][x+fx-1] ----
    float b2r[4];
    int fyr[4], fxr[4];
    #pragma unroll
    for (int r2 = 0; r2 < 4; ++r2) {
        int f = kg * 4 + r2;
        b2r[r2] = (f < 9) ? b2[f] : 0.f;
        int fy = f / 3;
        fyr[r2] = fy; fxr[r2] = f - fy * 3;
    }
    #pragma unroll
    for (int i = 0; i < 4; ++i) {
        int py = wv * 4 + i;
        float partial = 0.f;
        #pragma unroll
        for (int r2 = 0; r2 < 4; ++r2) {
            float img = xs[0][py + fyr[r2] + 3][n + fxr[r2] + 3];
            partial += (acc[i][r2] + b2r[r2]) * img;   // exact-zero term for f>=9
        }
        partial += __shfl_down(partial, 16, 64);
        partial += __shfl_down(partial, 32, 64);
        if (lane < 16)
            out[((size_t)b * HH + gy0 + py) * WW + gx0 + n] = partial;
    }
}

extern "C" void kernel_launch(void* const* d_in, const int* in_sizes, int n_in,
                              void* d_out, int out_size, void* d_ws, size_t ws_size,
                              hipStream_t stream) {
    const float* image = (const float*)d_in[0];
    const float* refer = (const float*)d_in[1];
    const float* w1    = (const float*)d_in[2];
    const float* b1    = (const float*)d_in[3];
    const float* w2    = (const float*)d_in[4];
    const float* b2    = (const float*)d_in[5];

    float* w1t = (float*)d_ws;                                   // 6.4 KB
    unsigned short* w2t = (unsigned short*)((char*)d_ws + 8192); // 28.7 KB
    // ws re-poisoned before every launch -> prep must (and does) run every call

    hipLaunchKernelGGL(dynfilt_prep, dim3(1), dim3(256), 0, stream, w1, w2, w1t, w2t);

    dim3 grid(WW / TILE, HH / TILE, 8);
    hipLaunchKernelGGL(dynfilt_main, grid, dim3(256), 0, stream,
                       image, refer, b1, b2, w1t, w2t, (float*)d_out);
}

// Round 9
// 198.709 us; speedup vs baseline: 4.3423x; 1.3117x over previous
//
#include <hip/hip_runtime.h>
#include <hip/hip_bf16.h>

// DynamicFilter fused, R9 = R8 + fix: zero the 16B uninitialized ubuf tail.
//
// R8 NaN'd: conv1 A-fragment for kg=3,s=1 reads shorts 56..63 of each xcol
// row = first 8 shorts of the NEXT row (harmless, finite, x B rows k>=50 are
// zero) -- except px=399, whose overrun lands in ubuf[44800:44816], never
// written. Stale LDS bits decoding as bf16 Inf/NaN give 0*Inf=NaN through
// the MFMA. Fix: explicitly zero that tail before the xcol barrier.
//
// Structure (R8): conv1 AND conv2 on mfma_f32_16x16x32_bf16.
//  * xcol[400px][56k] bf16 im2col (k=2*tap+ci; k>=50 zero via w1c B rows).
//  * conv1 GEMM D[px][ch]: 25 M-tiles x 2 N-tiles x 2 K-steps, D in regs.
//  * h = leaky(D+b1), OOB px zeroed, packed (ch n, ch n+16) -> hs[px][chpos];
//    w2t chpos-permuted to match. hs ALIASES xcol (barrier-separated).
//  * conv2: tap-quad GEMM (R7-verified): 7 quad-sets x 4 ch-groups x 4 tiles.
//  * epilogue: f=kg*4+r2, shfl_down(16/32) reduce, lanes 0-15 store.
// LDS: xs 4.6KB + ubuf 44.8KB = 49.4KB -> 3 blocks/CU.
// d_ws: w1c bf16 [32ch][64k] @0 (4KB), w2t bf16 [28tap][16f][32chpos] @4096.

typedef __attribute__((ext_vector_type(8))) short bf16x8;
typedef __attribute__((ext_vector_type(4))) float f32x4;

#define HH 512
#define WW 512
#define TILE 16
#define XS_H 24
#define XS_W 24
#define HS_R 20
#define HS_C 20
#define HSTRIDE 40            // shorts per px in hs (32 used) -> 80B
#define XCS 56                // shorts per px in xcol (50 used) -> 112B
#define UBYTES (400 * XCS * 2 + 16)   // 44816: xcol + 16B A-read overrun tail

__device__ __forceinline__ unsigned short f2bf(float x) {
    union { float f; unsigned int u; } v; v.f = x;
    unsigned int u = v.u;
    u += 0x7FFFu + ((u >> 16) & 1u);   // round-to-nearest-even
    return (unsigned short)(u >> 16);
}

__device__ __forceinline__ unsigned int pack_bf2(float a, float b) {
    // a -> low 16 bits, b -> high 16 bits (bf16 RNE)
    __hip_bfloat162 h2 = __float22bfloat162_rn(make_float2(a, b));
    union { __hip_bfloat162 h; unsigned int u; } cv; cv.h = h2;
    return cv.u;
}

__global__ void dynfilt_prep(const float* __restrict__ w1,
                             const float* __restrict__ w2,
                             unsigned short* __restrict__ w1c,
                             unsigned short* __restrict__ w2t)
{
    int gid = blockIdx.x * 256 + threadIdx.x;   // 8192 threads
    // w1c[ch32][k64]: k = 2*tap + ci; k>=50 -> 0 (kills im2col pad/garbage)
    for (int i = gid; i < 32 * 64; i += 8192) {
        int ch = i >> 6, k = i & 63;
        int tap = k >> 1, ci = k & 1;
        w1c[i] = (k < 50) ? f2bf(w1[(ch * 2 + ci) * 25 + tap]) : (unsigned short)0;
    }
    // w2t[tap28][f16][chpos32]: chpos 2i -> ch i, 2i+1 -> ch 16+i (matches hs
    // packing); taps>=25 / f>=9 zero.
    for (int i = gid; i < 28 * 16 * 32; i += 8192) {
        int p = i & 31;
        int f = (i >> 5) & 15;
        int tap = i >> 9;
        int ch = (p & 1) * 16 + (p >> 1);
        unsigned short v = 0;
        if (tap < 25 && f < 9) v = f2bf(w2[(f * 32 + ch) * 25 + tap]);
        w2t[i] = v;
    }
}

__global__
__attribute__((amdgpu_flat_work_group_size(256, 256), amdgpu_waves_per_eu(3)))
void dynfilt_main(const float* __restrict__ image,
                  const float* __restrict__ refer,
                  const float* __restrict__ b1,
                  const float* __restrict__ b2,
                  const unsigned short* __restrict__ w1c,
                  const unsigned short* __restrict__ w2t,
                  float* __restrict__ out)
{
    __shared__ float xs[2][XS_H][XS_W];
    __shared__ __align__(16) unsigned char ubuf[UBYTES];
    unsigned short* xcol = (unsigned short*)ubuf;   // [400][56] shorts
    unsigned short* hs   = (unsigned short*)ubuf;   // [400][40] shorts (aliased)

    const int t   = threadIdx.x;
    const int gx0 = blockIdx.x * TILE;
    const int gy0 = blockIdx.y * TILE;
    const int b   = blockIdx.z;

    // ---- stage x halo: rows gy0-4..gy0+19, cols gx0-4..gx0+19, 2 ch ----
    for (int idx = t; idx < 2 * XS_H * XS_W; idx += 256) {
        int ci  = idx / (XS_H * XS_W);
        int rem = idx - ci * (XS_H * XS_W);
        int r = rem / XS_W, c = rem - r * XS_W;
        int gy = gy0 - 4 + r, gx = gx0 - 4 + c;
        float v = 0.f;
        if ((unsigned)gy < HH && (unsigned)gx < WW)
            v = (ci ? refer : image)[((size_t)b * HH + gy) * WW + gx];
        (&xs[0][0][0])[idx] = v;
    }
    // R9 fix: zero the A-read overrun tail (px=399, kg=3, s=1 reads it)
    if (t == 0)
        *(uint4*)(ubuf + 400 * XCS * 2) = make_uint4(0u, 0u, 0u, 0u);
    __syncthreads();   // xs ready

    // ---- build xcol: per px, 25 tap-pairs (ci0,ci1) packed bf16 ----
    #pragma unroll 1
    for (int it = 0; it < 2; ++it) {
        int px = it * 256 + t;
        if (px < HS_R * HS_C) {
            int r = px / HS_C, c = px - (px / HS_C) * HS_C;
            unsigned int pk[28];
            #pragma unroll
            for (int dy = 0; dy < 5; ++dy) {
                const float* x0 = &xs[0][r + dy][c];
                const float* x1 = &xs[1][r + dy][c];
                #pragma unroll
                for (int dx = 0; dx < 5; ++dx)
                    pk[dy * 5 + dx] = pack_bf2(x0[dx], x1[dx]);
            }
            pk[25] = pk[26] = pk[27] = 0;
            unsigned int* dst = (unsigned int*)(xcol + px * XCS);
            #pragma unroll
            for (int w8 = 0; w8 < 7; ++w8)
                ((uint4*)dst)[w8] = make_uint4(pk[4 * w8], pk[4 * w8 + 1],
                                               pk[4 * w8 + 2], pk[4 * w8 + 3]);
        }
    }
    __syncthreads();   // xcol ready

    const int lane = t & 63;
    const int wv   = t >> 6;
    const int n    = lane & 15;
    const int kg   = lane >> 4;

    // ---- conv1 GEMM: D[px][ch], 25 M-tiles (wave w: w, w+4, ...) ----
    bf16x8 bfr[2][2];   // w1c B-frags [ntile][kstep], global (L1-hot)
    #pragma unroll
    for (int nt = 0; nt < 2; ++nt)
        #pragma unroll
        for (int s = 0; s < 2; ++s)
            bfr[nt][s] = *(const bf16x8*)(w1c + (nt * 16 + n) * 64 + s * 32 + kg * 8);

    f32x4 d[7][2];
    #pragma unroll
    for (int m = 0; m < 7; ++m) {
        d[m][0] = (f32x4){0.f, 0.f, 0.f, 0.f};
        d[m][1] = (f32x4){0.f, 0.f, 0.f, 0.f};
    }
    #pragma unroll
    for (int m = 0; m < 7; ++m) {
        int mt = m * 4 + wv;
        if (mt < 25) {   // wave-uniform guard
            const unsigned short* ap = xcol + (mt * 16 + n) * XCS;
            bf16x8 a0 = *(const bf16x8*)(ap + kg * 8);        // k 0..31
            bf16x8 a1 = *(const bf16x8*)(ap + 32 + kg * 8);   // k 32..63 (tail zero via B)
            d[m][0] = __builtin_amdgcn_mfma_f32_16x16x32_bf16(a0, bfr[0][0], d[m][0], 0, 0, 0);
            d[m][0] = __builtin_amdgcn_mfma_f32_16x16x32_bf16(a1, bfr[0][1], d[m][0], 0, 0, 0);
            d[m][1] = __builtin_amdgcn_mfma_f32_16x16x32_bf16(a0, bfr[1][0], d[m][1], 0, 0, 0);
            d[m][1] = __builtin_amdgcn_mfma_f32_16x16x32_bf16(a1, bfr[1][1], d[m][1], 0, 0, 0);
        }
    }
    __syncthreads();   // all A-reads done; xcol dead -> hs may overlay

    // ---- h write-back: bias + leaky + OOB-zero, pack (ch n, ch n+16) ----
    {
        float bb0 = b1[n], bb1 = b1[16 + n];
        #pragma unroll
        for (int m = 0; m < 7; ++m) {
            int mt = m * 4 + wv;
            if (mt < 25) {
                #pragma unroll
                for (int r = 0; r < 4; ++r) {
                    int px = mt * 16 + kg * 4 + r;   // D row = (lane>>4)*4 + reg
                    int pr = px / HS_C, pc = px - pr * HS_C;
                    int gy = gy0 - 2 + pr, gx = gx0 - 2 + pc;
                    bool inb = ((unsigned)gy < HH) & ((unsigned)gx < WW);
                    float h0 = d[m][0][r] + bb0;
                    float h1 = d[m][1][r] + bb1;
                    h0 = (h0 >= 0.f) ? h0 : 0.1f * h0;
                    h1 = (h1 >= 0.f) ? h1 : 0.1f * h1;
                    if (!inb) { h0 = 0.f; h1 = 0.f; }
                    *(unsigned int*)(hs + px * HSTRIDE + 2 * n) = pack_bf2(h0, h1);
                }
            }
        }
    }
    __syncthreads();   // hs ready

    // ---- conv2: tap-quad MFMA GEMM (R7-verified), chpos order via w2t ----
    int bofs[7];
    #pragma unroll
    for (int q = 0; q < 7; ++q) {
        int tap = 4 * q + kg;
        if (tap > 24) tap = 0;          // pad tap: A rows zero in w2t
        int dy = tap / 5, dx = tap - dy * 5;
        bofs[q] = (dy * HS_C + dx) * (HSTRIDE * 2);
    }
    const char* bb[4];
    #pragma unroll
    for (int i = 0; i < 4; ++i)
        bb[i] = (const char*)hs + ((wv * 4 + i) * HS_C + n) * (HSTRIDE * 2);

    f32x4 acc[4];
    #pragma unroll
    for (int i = 0; i < 4; ++i) acc[i] = (f32x4){0.f, 0.f, 0.f, 0.f};

    #pragma unroll
    for (int q = 0; q < 7; ++q) {
        bf16x8 afr[4];
        #pragma unroll
        for (int g = 0; g < 4; ++g)
            afr[g] = *(const bf16x8*)(w2t + ((4 * q + kg) * 16 + n) * 32 + g * 8);
        #pragma unroll
        for (int i = 0; i < 4; ++i) {
            const char* ba = bb[i] + bofs[q];
            #pragma unroll
            for (int g = 0; g < 4; ++g) {
                bf16x8 bfrag = *(const bf16x8*)(ba + g * 16);
                acc[i] = __builtin_amdgcn_mfma_f32_16x16x32_bf16(afr[g], bfrag, acc[i], 0, 0, 0);
            }
        }
    }

    // ---- epilogue: out = sum_f (filt_f + b2_f) * image[y+fy-1][x+fx-1] ----
    float b2r[4];
    int fyr[4], fxr[4];
    #pragma unroll
    for (int r2 = 0; r2 < 4; ++r2) {
        int f = kg * 4 + r2;
        b2r[r2] = (f < 9) ? b2[f] : 0.f;
        int fy = f / 3;
        fyr[r2] = fy; fxr[r2] = f - fy * 3;
    }
    #pragma unroll
    for (int i = 0; i < 4; ++i) {
        int py = wv * 4 + i;
        float partial = 0.f;
        #pragma unroll
        for (int r2 = 0; r2 < 4; ++r2) {
            float img = xs[0][py + fyr[r2] + 3][n + fxr[r2] + 3];
            partial += (acc[i][r2] + b2r[r2]) * img;   // exact-zero term for f>=9
        }
        partial += __shfl_down(partial, 16, 64);
        partial += __shfl_down(partial, 32, 64);
        if (lane < 16)
            out[((size_t)b * HH + gy0 + py) * WW + gx0 + n] = partial;
    }
}

extern "C" void kernel_launch(void* const* d_in, const int* in_sizes, int n_in,
                              void* d_out, int out_size, void* d_ws, size_t ws_size,
                              hipStream_t stream) {
    const float* image = (const float*)d_in[0];
    const float* refer = (const float*)d_in[1];
    const float* w1    = (const float*)d_in[2];
    const float* b1    = (const float*)d_in[3];
    const float* w2    = (const float*)d_in[4];
    const float* b2    = (const float*)d_in[5];

    unsigned short* w1c = (unsigned short*)d_ws;                   // 4 KB
    unsigned short* w2t = (unsigned short*)((char*)d_ws + 4096);   // 28.7 KB
    // ws re-poisoned before every launch -> prep must (and does) run every call

    hipLaunchKernelGGL(dynfilt_prep, dim3(32), dim3(256), 0, stream, w1, w2, w1c, w2t);

    dim3 grid(WW / TILE, HH / TILE, 8);
    hipLaunchKernelGGL(dynfilt_main, grid, dim3(256), 0, stream,
                       image, refer, b1, b2, w1c, w2t, (float*)d_out);
}